// Round 5
// baseline (69.687 us; speedup 1.0000x reference)
//
#include <hip/hip_runtime.h>
#include <hip/hip_bf16.h>

// B=1024, D=512, K=256, NC=1.
// out[b,k] = sum_d (x-m)^2 * 0.5*softplus(rho)^2
//          = sum_d w*x^2 + a2*x + c[k],  w=0.5*sp^2, a2=-2*w*m, c=sum_d w*m^2
// => GEMM: out = X' W'^T + c, X'=[x^2,x] (B x 1024 bf16), W'=[w,a2] (K x 1024 bf16)
// 2 dispatches: fused prep (X' + W' + c), then MFMA GEMM with dual acc chains.

#define BB 1024
#define DD 512
#define DP 1024
#define KK 256
#define PREP_X_BLOCKS 256   // each thread: 2 float4 of x
#define PREP_W_BLOCKS 128   // 2 k-rows per block

typedef __attribute__((ext_vector_type(8))) short bf16x8;
typedef __attribute__((ext_vector_type(4))) float f32x4;
typedef __attribute__((ext_vector_type(4))) unsigned short us4;

static __device__ inline unsigned short f2bf(float f) {
    __hip_bfloat16 h = __float2bfloat16(f);
    return *reinterpret_cast<unsigned short*>(&h);
}

static __device__ inline void conv_x4(const float4 v, us4& sq, us4& ln) {
    sq.x = f2bf(v.x * v.x); sq.y = f2bf(v.y * v.y);
    sq.z = f2bf(v.z * v.z); sq.w = f2bf(v.w * v.w);
    ln.x = f2bf(v.x); ln.y = f2bf(v.y); ln.z = f2bf(v.z); ln.w = f2bf(v.w);
}

__global__ __launch_bounds__(256) void prep_kernel(const float* __restrict__ x,
                                                   const float* __restrict__ means,
                                                   const float* __restrict__ rho,
                                                   unsigned short* __restrict__ Xp,
                                                   unsigned short* __restrict__ Wp,
                                                   float* __restrict__ c) {
    const int t = threadIdx.x;
    if (blockIdx.x < PREP_X_BLOCKS) {
        // ---- X': each thread handles 8 consecutive floats of one x row ----
        const int i = blockIdx.x * 256 + t;     // 65536 threads
        const int b  = i >> 6;                  // 64 groups of 8 per row
        const int d8 = (i & 63) * 8;
        const float4 v0 = *(const float4*)&x[b * DD + d8];
        const float4 v1 = *(const float4*)&x[b * DD + d8 + 4];
        us4 sq0, ln0, sq1, ln1;
        conv_x4(v0, sq0, ln0);
        conv_x4(v1, sq1, ln1);
        *(us4*)&Xp[b * DP + d8]          = sq0;
        *(us4*)&Xp[b * DP + d8 + 4]      = sq1;
        *(us4*)&Xp[b * DP + DD + d8]     = ln0;
        *(us4*)&Xp[b * DP + DD + d8 + 4] = ln1;
    } else {
        // ---- W' + c: 2 k-rows per block, 128 threads each ----
        __shared__ float red[256];
        const int blk  = blockIdx.x - PREP_X_BLOCKS;
        const int half = t >> 7;
        const int k    = blk * 2 + half;
        const int d4   = (t & 127) * 4;
        const float4 mv = *(const float4*)&means[k * DD + d4];
        const float4 rv = *(const float4*)&rho  [k * DD + d4];
        us4 wq, aq;
        float sp, wv, csum = 0.f;
        sp = log1pf(expf(rv.x)); wv = 0.5f * sp * sp;
        wq.x = f2bf(wv); aq.x = f2bf(-2.f * wv * mv.x); csum += wv * mv.x * mv.x;
        sp = log1pf(expf(rv.y)); wv = 0.5f * sp * sp;
        wq.y = f2bf(wv); aq.y = f2bf(-2.f * wv * mv.y); csum += wv * mv.y * mv.y;
        sp = log1pf(expf(rv.z)); wv = 0.5f * sp * sp;
        wq.z = f2bf(wv); aq.z = f2bf(-2.f * wv * mv.z); csum += wv * mv.z * mv.z;
        sp = log1pf(expf(rv.w)); wv = 0.5f * sp * sp;
        wq.w = f2bf(wv); aq.w = f2bf(-2.f * wv * mv.w); csum += wv * mv.w * mv.w;
        *(us4*)&Wp[k * DP + d4]      = wq;
        *(us4*)&Wp[k * DP + DD + d4] = aq;
        red[t] = csum;
        __syncthreads();
        if (t < 2) {
            float s = 0.f;
#pragma unroll
            for (int j = 0; j < 128; j++) s += red[t * 128 + j];
            c[blk * 2 + t] = s;
        }
    }
}

// 1024 wave-tiles (16x16) in 512 blocks x 2 waves; dual independent acc chains.
__global__ __launch_bounds__(128) void gemm_kernel(const unsigned short* __restrict__ Xp,
                                                   const unsigned short* __restrict__ Wp,
                                                   const float* __restrict__ c,
                                                   float* __restrict__ out) {
    const int lane = threadIdx.x & 63;
    const int wave = threadIdx.x >> 6;
    const int tile = blockIdx.x * 2 + wave;   // 0..1023
    const int kb = tile & 15;
    const int bb = tile >> 4;
    const int k0 = kb * 16;
    const int b0 = bb * 16;

    const int rc   = lane & 15;
    const int quad = lane >> 4;

    const unsigned short* aRow = Xp + (b0 + rc) * DP + quad * 8;
    const unsigned short* bRow = Wp + (k0 + rc) * DP + quad * 8;

    f32x4 acc0 = {0.f, 0.f, 0.f, 0.f};
    f32x4 acc1 = {0.f, 0.f, 0.f, 0.f};
#pragma unroll 8
    for (int dk = 0; dk < DP; dk += 64) {
        const bf16x8 a0 = *(const bf16x8*)(aRow + dk);
        const bf16x8 b0v = *(const bf16x8*)(bRow + dk);
        const bf16x8 a1 = *(const bf16x8*)(aRow + dk + 32);
        const bf16x8 b1v = *(const bf16x8*)(bRow + dk + 32);
        acc0 = __builtin_amdgcn_mfma_f32_16x16x32_bf16(a0, b0v, acc0, 0, 0, 0);
        acc1 = __builtin_amdgcn_mfma_f32_16x16x32_bf16(a1, b1v, acc1, 0, 0, 0);
    }

    const float cv = c[k0 + rc];
#pragma unroll
    for (int r = 0; r < 4; r++) {
        out[(b0 + quad * 4 + r) * KK + (k0 + rc)] = acc0[r] + acc1[r] + cv;
    }
}

extern "C" void kernel_launch(void* const* d_in, const int* in_sizes, int n_in,
                              void* d_out, int out_size, void* d_ws, size_t ws_size,
                              hipStream_t stream) {
    const float* x     = (const float*)d_in[0];
    const float* means = (const float*)d_in[1];
    const float* rho   = (const float*)d_in[2];
    float* out = (float*)d_out;

    unsigned short* Xp = (unsigned short*)d_ws;         // 2 MB
    unsigned short* Wp = Xp + (size_t)BB * DP;          // 512 KB
    float* c = (float*)(Wp + (size_t)KK * DP);          // 1 KB

    prep_kernel<<<PREP_X_BLOCKS + PREP_W_BLOCKS, 256, 0, stream>>>(x, means, rho, Xp, Wp, c);
    gemm_kernel<<<512, 128, 0, stream>>>(Xp, Wp, c, out);
}

// Round 6
// 68.831 us; speedup vs baseline: 1.0124x; 1.0124x over previous
//
#include <hip/hip_runtime.h>
#include <hip/hip_bf16.h>

// B=1024, D=512, K=256, NC=1.
// out[b,k] = sum_d (x-m)^2 * 0.5*softplus(rho)^2
//          = sum_d w*x^2 + a2*x + c[k],  w=0.5*sp^2, a2=-2*w*m, c=sum_d w*m^2
// => GEMM: out = X' W'^T + c, X'=[x^2,x] (B x 1024 bf16), W'=[w,a2] (K x 1024 bf16)
// Best-measured config (R4, 68.9 us): fused prep dispatch + 256-block MFMA GEMM.
// Timed region is dominated by harness resets (256 MB ws poison fill ~41 us @ ~80%
// HBM peak); our two dispatches are ~6-8 us including launch overhead.

#define BB 1024
#define DD 512
#define DP 1024
#define KK 256
#define PREP_X_BLOCKS 512   // (1024*512/4)/256
#define PREP_W_BLOCKS 128   // 2 k-rows per block

typedef __attribute__((ext_vector_type(8))) short bf16x8;
typedef __attribute__((ext_vector_type(4))) float f32x4;
typedef __attribute__((ext_vector_type(4))) unsigned short us4;

static __device__ inline unsigned short f2bf(float f) {
    __hip_bfloat16 h = __float2bfloat16(f);
    return *reinterpret_cast<unsigned short*>(&h);
}

__global__ __launch_bounds__(256) void prep_kernel(const float* __restrict__ x,
                                                   const float* __restrict__ means,
                                                   const float* __restrict__ rho,
                                                   unsigned short* __restrict__ Xp,
                                                   unsigned short* __restrict__ Wp,
                                                   float* __restrict__ c) {
    const int t = threadIdx.x;
    if (blockIdx.x < PREP_X_BLOCKS) {
        // ---- X' ----
        const int i = blockIdx.x * 256 + t;
        const int b  = i >> 7;
        const int d4 = (i & 127) * 4;
        const float4 xv = *(const float4*)&x[b * DD + d4];
        us4 sq, ln;
        sq.x = f2bf(xv.x * xv.x); sq.y = f2bf(xv.y * xv.y);
        sq.z = f2bf(xv.z * xv.z); sq.w = f2bf(xv.w * xv.w);
        ln.x = f2bf(xv.x); ln.y = f2bf(xv.y); ln.z = f2bf(xv.z); ln.w = f2bf(xv.w);
        *(us4*)&Xp[b * DP + d4]      = sq;
        *(us4*)&Xp[b * DP + DD + d4] = ln;
    } else {
        // ---- W' + c: 2 k-rows per block, 128 threads each ----
        __shared__ float red[256];
        const int blk  = blockIdx.x - PREP_X_BLOCKS;
        const int half = t >> 7;             // 0/1
        const int k    = blk * 2 + half;
        const int d4   = (t & 127) * 4;
        const float4 mv = *(const float4*)&means[k * DD + d4];
        const float4 rv = *(const float4*)&rho  [k * DD + d4];
        us4 wq, aq;
        float sp, wv, csum = 0.f;
        sp = log1pf(expf(rv.x)); wv = 0.5f * sp * sp;
        wq.x = f2bf(wv); aq.x = f2bf(-2.f * wv * mv.x); csum += wv * mv.x * mv.x;
        sp = log1pf(expf(rv.y)); wv = 0.5f * sp * sp;
        wq.y = f2bf(wv); aq.y = f2bf(-2.f * wv * mv.y); csum += wv * mv.y * mv.y;
        sp = log1pf(expf(rv.z)); wv = 0.5f * sp * sp;
        wq.z = f2bf(wv); aq.z = f2bf(-2.f * wv * mv.z); csum += wv * mv.z * mv.z;
        sp = log1pf(expf(rv.w)); wv = 0.5f * sp * sp;
        wq.w = f2bf(wv); aq.w = f2bf(-2.f * wv * mv.w); csum += wv * mv.w * mv.w;
        *(us4*)&Wp[k * DD * 2 / 1 + d4] = wq;   // k * DP + d4
        *(us4*)&Wp[k * DP + DD + d4] = aq;
        red[t] = csum;
        __syncthreads();
        if (t < 2) {
            float s = 0.f;
#pragma unroll
            for (int j = 0; j < 128; j++) s += red[t * 128 + j];
            c[blk * 2 + t] = s;
        }
    }
}

// 1024 wave-tiles (16x16) = 256 blocks x 4 waves; K-loop over DP=1024.
__global__ __launch_bounds__(256) void gemm_kernel(const unsigned short* __restrict__ Xp,
                                                   const unsigned short* __restrict__ Wp,
                                                   const float* __restrict__ c,
                                                   float* __restrict__ out) {
    const int lane = threadIdx.x & 63;
    const int wave = threadIdx.x >> 6;
    const int tile = blockIdx.x * 4 + wave;   // 0..1023
    const int kb = tile & 15;
    const int bb = tile >> 4;
    const int k0 = kb * 16;
    const int b0 = bb * 16;

    const int rc   = lane & 15;
    const int quad = lane >> 4;

    const unsigned short* aRow = Xp + (b0 + rc) * DP + quad * 8;
    const unsigned short* bRow = Wp + (k0 + rc) * DP + quad * 8;

    f32x4 acc = {0.f, 0.f, 0.f, 0.f};
#pragma unroll 8
    for (int dk = 0; dk < DP; dk += 32) {
        const bf16x8 a = *(const bf16x8*)(aRow + dk);
        const bf16x8 b = *(const bf16x8*)(bRow + dk);
        acc = __builtin_amdgcn_mfma_f32_16x16x32_bf16(a, b, acc, 0, 0, 0);
    }

    const float cv = c[k0 + rc];
#pragma unroll
    for (int r = 0; r < 4; r++) {
        out[(b0 + quad * 4 + r) * KK + (k0 + rc)] = acc[r] + cv;
    }
}

extern "C" void kernel_launch(void* const* d_in, const int* in_sizes, int n_in,
                              void* d_out, int out_size, void* d_ws, size_t ws_size,
                              hipStream_t stream) {
    const float* x     = (const float*)d_in[0];
    const float* means = (const float*)d_in[1];
    const float* rho   = (const float*)d_in[2];
    float* out = (float*)d_out;

    unsigned short* Xp = (unsigned short*)d_ws;         // 2 MB
    unsigned short* Wp = Xp + (size_t)BB * DP;          // 512 KB
    float* c = (float*)(Wp + (size_t)KK * DP);          // 1 KB

    prep_kernel<<<PREP_X_BLOCKS + PREP_W_BLOCKS, 256, 0, stream>>>(x, means, rho, Xp, Wp, c);
    gemm_kernel<<<256, 256, 0, stream>>>(Xp, Wp, c, out);
}